// Round 1
// 1038.612 us; speedup vs baseline: 1.3343x; 1.3343x over previous
//
#include <hip/hip_runtime.h>

#define N_P 100000
#define N_A 50000
#define DD  64
#define E_W 800000
#define E_C 1200000
#define E_TOT (E_W + E_C)

#define SCAN_TOT (2 * N_P)
#define SCAN_CHUNK 2048
#define NCH ((SCAN_TOT + SCAN_CHUNK - 1) / SCAN_CHUNK)  // 98

// ---------------- K1: degree histograms (int atomics) ----------------
__global__ __launch_bounds__(256) void k_degrees(
    const int* __restrict__ wsrc, const int* __restrict__ wdst,
    const int* __restrict__ csrc, const int* __restrict__ cdst,
    unsigned* __restrict__ deg_a, unsigned* __restrict__ deg_p,
    unsigned* __restrict__ cnt2) {
    int t = blockIdx.x * blockDim.x + threadIdx.x;
    if (t < E_W) {
        atomicAdd(&deg_a[wsrc[t]], 1u);
        atomicAdd(&cnt2[wdst[t]], 1u);
    }
    if (t < E_C) {
        atomicAdd(&deg_p[csrc[t]], 1u);
        atomicAdd(&cnt2[N_P + cdst[t]], 1u);
    }
}

// ---------------- K2a: per-chunk local exclusive scan ----------------
__global__ __launch_bounds__(256) void k_scan_local(
    const unsigned* __restrict__ cnt2, unsigned* __restrict__ offs,
    unsigned* __restrict__ chunkSum) {
    __shared__ unsigned lds[256];
    const int b = blockIdx.x, t = threadIdx.x;
    const int base = b * SCAN_CHUNK + t * 8;
    unsigned v[8];
    unsigned s = 0;
    if (base + 8 <= SCAN_TOT) {
        uint4 a0 = *reinterpret_cast<const uint4*>(&cnt2[base]);
        uint4 a1 = *reinterpret_cast<const uint4*>(&cnt2[base + 4]);
        v[0] = a0.x; v[1] = a0.y; v[2] = a0.z; v[3] = a0.w;
        v[4] = a1.x; v[5] = a1.y; v[6] = a1.z; v[7] = a1.w;
#pragma unroll
        for (int i = 0; i < 8; ++i) s += v[i];
    } else {
#pragma unroll
        for (int i = 0; i < 8; ++i) {
            int idx = base + i;
            v[i] = (idx < SCAN_TOT) ? cnt2[idx] : 0u;
            s += v[i];
        }
    }
    lds[t] = s;
    __syncthreads();
    for (int off = 1; off < 256; off <<= 1) {
        unsigned w = (t >= off) ? lds[t - off] : 0u;
        __syncthreads();
        lds[t] += w;
        __syncthreads();
    }
    unsigned run = lds[t] - s;  // exclusive prefix for this thread's first elem
#pragma unroll
    for (int i = 0; i < 8; ++i) {
        int idx = base + i;
        if (idx < SCAN_TOT) offs[idx] = run;
        run += v[i];
    }
    if (t == 255) chunkSum[b] = lds[255];
}

// ---------------- K2b: scan the 98 chunk sums ----------------
__global__ __launch_bounds__(128) void k_scan_chunks(
    const unsigned* __restrict__ chunkSum, unsigned* __restrict__ chunkOff) {
    __shared__ unsigned lds[128];
    const int t = threadIdx.x;
    unsigned v = (t < NCH) ? chunkSum[t] : 0u;
    lds[t] = v;
    __syncthreads();
    for (int off = 1; off < 128; off <<= 1) {
        unsigned w = (t >= off) ? lds[t - off] : 0u;
        __syncthreads();
        lds[t] += w;
        __syncthreads();
    }
    if (t < NCH) chunkOff[t] = lds[t] - v;  // exclusive
}

// ---------------- K2c: apply chunk offsets, init cursors ----------------
__global__ __launch_bounds__(256) void k_scan_apply(
    unsigned* __restrict__ offs, const unsigned* __restrict__ chunkOff,
    unsigned* __restrict__ cursor) {
    int i = blockIdx.x * blockDim.x + threadIdx.x;
    if (i < SCAN_TOT) {
        unsigned o = offs[i] + chunkOff[i / SCAN_CHUNK];
        offs[i] = o;
        cursor[i] = o;
    }
}

// ---------------- K3: fill CSR (src index + edge id per slot) ----------------
__global__ __launch_bounds__(256) void k_fill(
    const int* __restrict__ wsrc, const int* __restrict__ wdst,
    const int* __restrict__ csrc, const int* __restrict__ cdst,
    unsigned* __restrict__ cursor, int* __restrict__ idx_src,
    int* __restrict__ idx_eid) {
    int t = blockIdx.x * blockDim.x + threadIdx.x;
    if (t < E_W) {
        int d = wdst[t];
        unsigned p = atomicAdd(&cursor[d], 1u);
        idx_src[p] = wsrc[t];
        idx_eid[p] = t;
    }
    if (t < E_C) {
        int d = cdst[t];
        unsigned p = atomicAdd(&cursor[N_P + d], 1u);
        idx_src[p] = csrc[t];
        idx_eid[p] = t;
    }
}

// ---------------- K4: transform-first GEMVs ----------------
// ht_a  = (h_author @ Wra^T) * outdeg_a^-1/2        [N_A,64]
// ht_pc = (h_paper  @ Wrp^T) * outdeg_p^-1/2        [N_P,64]
// hl    =  h_paper  @ Wl^T + bl                     [N_P,64]
// One W row per lane in VGPRs; x rows are wave-uniform scalar loads.
__global__ __launch_bounds__(256) void k_transform(
    const float* __restrict__ h_author, const float* __restrict__ h_paper,
    const float* __restrict__ Wra, const float* __restrict__ Wrp,
    const float* __restrict__ Wl, const float* __restrict__ bl,
    const unsigned* __restrict__ deg_a, const unsigned* __restrict__ deg_p,
    float* __restrict__ ht_a, float* __restrict__ ht_pc,
    float* __restrict__ hl_b) {
    const int lane = threadIdx.x & 63;
    const int wib = threadIdx.x >> 6;
    const int b = blockIdx.x;
    int seg, nrows, nwaves, wave;
    const float* W;
    const float* X;
    float* O;
    if (b < 192)      { seg = 0; W = Wra; X = h_author; O = ht_a;  nrows = N_A; nwaves = 192 * 4; wave = b * 4 + wib; }
    else if (b < 576) { seg = 1; W = Wrp; X = h_paper;  O = ht_pc; nrows = N_P; nwaves = 384 * 4; wave = (b - 192) * 4 + wib; }
    else              { seg = 2; W = Wl;  X = h_paper;  O = hl_b;  nrows = N_P; nwaves = 448 * 4; wave = (b - 576) * 4 + wib; }

    float wrow[DD];
#pragma unroll
    for (int k = 0; k < DD; ++k) wrow[k] = W[(size_t)lane * DD + k];
    const float bias = (seg == 2) ? bl[lane] : 0.f;

    for (int r = wave; r < nrows; r += nwaves) {
        const int ur = __builtin_amdgcn_readfirstlane(r);
        const float* x = X + (size_t)ur * DD;
        float acc = 0.f;
#pragma unroll
        for (int k = 0; k < DD; ++k) acc = fmaf(x[k], wrow[k], acc);
        float outv;
        if (seg == 0)      outv = acc * rsqrtf(fmaxf((float)deg_a[ur], 1.f));
        else if (seg == 1) outv = acc * rsqrtf(fmaxf((float)deg_p[ur], 1.f));
        else               outv = acc + bias;
        O[(size_t)ur * DD + lane] = outv;
    }
}

// ---------------- K5: fused CSR pull-aggregate + elu + softmax + edge write ----
// One wave per paper node. lane = feature. No atomics, no W access, no att
// intermediates: attention values are written straight to the per-edge output.
__global__ __launch_bounds__(256) void k_node_agg(
    const float* __restrict__ ht_a, const float* __restrict__ ht_pc,
    const float* __restrict__ hl_b,
    const float* __restrict__ bra, const float* __restrict__ brp,
    const unsigned* __restrict__ cnt2, const unsigned* __restrict__ offs,
    const int* __restrict__ idx_src, const int* __restrict__ idx_eid,
    float* __restrict__ out) {
    const int lane = threadIdx.x & 63;
    const int wv = __builtin_amdgcn_readfirstlane(blockIdx.x * 4 + (threadIdx.x >> 6));
    if (wv >= N_P) return;
    const int n = wv;
    const int cw = (int)cnt2[n];
    const int cc = (int)cnt2[N_P + n];
    if ((cw | cc) == 0) return;  // isolated node: owns no output rows
    const int ow = (int)offs[n];
    const int oc = (int)offs[N_P + n];

    const float hlv = hl_b[(size_t)n * DD + lane];

    float accw = 0.f;
    {
        int j = 0;
        for (; j + 4 <= cw; j += 4) {
            int s0 = idx_src[ow + j], s1 = idx_src[ow + j + 1];
            int s2 = idx_src[ow + j + 2], s3 = idx_src[ow + j + 3];
            float v0 = ht_a[(size_t)s0 * DD + lane];
            float v1 = ht_a[(size_t)s1 * DD + lane];
            float v2 = ht_a[(size_t)s2 * DD + lane];
            float v3 = ht_a[(size_t)s3 * DD + lane];
            accw += (v0 + v1) + (v2 + v3);
        }
        for (; j < cw; ++j) accw += ht_a[(size_t)idx_src[ow + j] * DD + lane];
    }
    float accc = 0.f;
    {
        int j = 0;
        for (; j + 4 <= cc; j += 4) {
            int s0 = idx_src[oc + j], s1 = idx_src[oc + j + 1];
            int s2 = idx_src[oc + j + 2], s3 = idx_src[oc + j + 3];
            float v0 = ht_pc[(size_t)s0 * DD + lane];
            float v1 = ht_pc[(size_t)s1 * DD + lane];
            float v2 = ht_pc[(size_t)s2 * DD + lane];
            float v3 = ht_pc[(size_t)s3 * DD + lane];
            accc += (v0 + v1) + (v2 + v3);
        }
        for (; j < cc; ++j) accc += ht_pc[(size_t)idx_src[oc + j] * DD + lane];
    }

    const float cwf = (float)cw, ccf = (float)cc;
    const float hrw = accw * rsqrtf(fmaxf(cwf, 1.f)) + bra[lane];
    const float hrc = accc * rsqrtf(fmaxf(ccf, 1.f)) + brp[lane];
    const float xw = hlv + hrw;
    const float xc = hlv + hrc;
    const float eaw = (xw > 0.f) ? xw : expm1f(xw);  // elu
    const float eac = (xc > 0.f) ? xc : expm1f(xc);

    float aw, ac;
    if (cw > 0 && cc > 0) {
        float m = fmaxf(eaw, eac);
        float ew = __expf(eaw - m);
        float ec = __expf(eac - m);
        float z = cwf * ew + ccf * ec;
        aw = ew / z;
        ac = ec / z;
    } else if (cw > 0) {
        aw = 1.f / cwf; ac = 0.f;
    } else {
        ac = 1.f / ccf; aw = 0.f;
    }

    for (int j = 0; j < cw; ++j) {
        int e = idx_eid[ow + j];
        out[(size_t)e * DD + lane] = aw;
    }
    for (int j = 0; j < cc; ++j) {
        int e = idx_eid[oc + j];
        out[((size_t)(E_W + e)) * DD + lane] = ac;
    }
}

extern "C" void kernel_launch(void* const* d_in, const int* in_sizes, int n_in,
                              void* d_out, int out_size, void* d_ws, size_t ws_size,
                              hipStream_t stream) {
    const float* h_paper  = (const float*)d_in[0];
    const float* h_author = (const float*)d_in[1];
    const float* Wl  = (const float*)d_in[2];
    const float* bl  = (const float*)d_in[3];
    const float* Wra = (const float*)d_in[4];
    const float* bra = (const float*)d_in[5];
    const float* Wrp = (const float*)d_in[6];
    const float* brp = (const float*)d_in[7];
    const int* wsrc = (const int*)d_in[8];
    const int* wdst = (const int*)d_in[9];
    const int* csrc = (const int*)d_in[10];
    const int* cdst = (const int*)d_in[11];

    // workspace layout (~83 MB)
    float* ht_a  = (float*)d_ws;                       // N_A*64
    float* ht_pc = ht_a + (size_t)N_A * DD;            // N_P*64
    float* hl_b  = ht_pc + (size_t)N_P * DD;           // N_P*64
    int* idx_src = (int*)(hl_b + (size_t)N_P * DD);    // E_TOT
    int* idx_eid = idx_src + E_TOT;                    // E_TOT
    unsigned* deg_a  = (unsigned*)(idx_eid + E_TOT);   // N_A   (zeroed)
    unsigned* deg_p  = deg_a + N_A;                    // N_P   (zeroed)
    unsigned* cnt2   = deg_p + N_P;                    // 2*N_P (zeroed)
    unsigned* offs   = cnt2 + SCAN_TOT;                // 2*N_P
    unsigned* cursor = offs + SCAN_TOT;                // 2*N_P
    unsigned* chunkSum = cursor + SCAN_TOT;            // 128
    unsigned* chunkOff = chunkSum + 128;               // 128

    hipMemsetAsync(deg_a, 0, (size_t)(N_A + N_P + SCAN_TOT) * sizeof(unsigned), stream);

    const int thr = 256;
    // K1: degrees + per-relation in-degree counts
    k_degrees<<<(E_C + thr - 1) / thr, thr, 0, stream>>>(wsrc, wdst, csrc, cdst,
                                                         deg_a, deg_p, cnt2);
    // K2: exclusive scan of concatenated counts -> CSR offsets (+cursor copy)
    k_scan_local<<<NCH, 256, 0, stream>>>(cnt2, offs, chunkSum);
    k_scan_chunks<<<1, 128, 0, stream>>>(chunkSum, chunkOff);
    k_scan_apply<<<(SCAN_TOT + 255) / 256, 256, 0, stream>>>(offs, chunkOff, cursor);
    // K3: scatter edges into CSR slots
    k_fill<<<(E_C + thr - 1) / thr, thr, 0, stream>>>(wsrc, wdst, csrc, cdst,
                                                      cursor, idx_src, idx_eid);
    // K4: transform-first GEMVs (3 segments in one launch)
    k_transform<<<1024, 256, 0, stream>>>(h_author, h_paper, Wra, Wrp, Wl, bl,
                                          deg_a, deg_p, ht_a, ht_pc, hl_b);
    // K5: fused pull-aggregate + softmax + direct per-edge output write
    k_node_agg<<<(N_P + 3) / 4, 256, 0, stream>>>(ht_a, ht_pc, hl_b, bra, brp,
                                                  cnt2, offs, idx_src, idx_eid,
                                                  (float*)d_out);
}